// Round 6
// baseline (157.119 us; speedup 1.0000x reference)
//
#include <hip/hip_runtime.h>
#include <math.h>

#define IC     2401
#define BSZ    256
#define OC     8
#define CS     16
#define OCC    128     // OC*CS
#define XROW   19208   // x row length (floats) = IC*8
#define KP     19264   // padded K (=301*64), pad zeroed
#define KTILES 301
#define NI     64      // split-K slices for s_gemm

typedef __attribute__((ext_vector_type(8))) short short8;
typedef __attribute__((ext_vector_type(4))) short short4v;
typedef __attribute__((ext_vector_type(4))) float f32x4;

__device__ __forceinline__ unsigned short f2bf(float f) {
    union { float f; unsigned u; } v; v.f = f;
    const unsigned r = v.u + 0x7FFF + ((v.u >> 16) & 1);   // RNE
    return (unsigned short)(r >> 16);
}
__device__ __forceinline__ float bf2f(unsigned short h) {
    union { unsigned u; float f; } v; v.u = ((unsigned)h) << 16;
    return v.f;
}

// ---------------- prep: blocks 0..1203 -> xT + xB ; 1204..1504 -> Wbf + cwt0.
// Blocks 0..95 additionally zero the three s accumulators (ws is poisoned).
__global__ __launch_bounds__(256)
void prep_kernel(const float* __restrict__ x, const float* __restrict__ W,
                 unsigned short* __restrict__ xT, unsigned short* __restrict__ xB,
                 unsigned short* __restrict__ Wbf, unsigned short* __restrict__ cwt,
                 float* __restrict__ sbuf)
{
    const int tid = threadIdx.x;
    if (blockIdx.x < 96)   // zero s0|s1|s2 : 3*32768 floats = 24576 float4
        ((float4*)sbuf)[blockIdx.x * 256 + tid] = make_float4(0.f, 0.f, 0.f, 0.f);

    if (blockIdx.x < 1204) {
        __shared__ float Ts[64 * 65];
        const int bg = blockIdx.x & 3;       // b-group of 64
        const int kt = blockIdx.x >> 2;      // k-tile 0..300
#pragma unroll
        for (int r = 0; r < 4; ++r) {
            const int flat = r * 256 + tid;  // 1024 float4s
            const int b = flat >> 4, cq = flat & 15;
            const int col = kt * 64 + cq * 4;
            float4 v = make_float4(0.f, 0.f, 0.f, 0.f);
            if (col < XROW) v = *(const float4*)(x + (size_t)(bg * 64 + b) * XROW + col);
            *(float4*)&Ts[b * 65 + cq * 4] = v;
        }
        __syncthreads();
        // xT[k][b]
#pragma unroll
        for (int r = 0; r < 2; ++r) {
            const int flat = r * 256 + tid;
            const int rl = flat >> 3, bq = flat & 7;
            union { short8 v; unsigned short h[8]; } o;
#pragma unroll
            for (int j = 0; j < 8; ++j) o.h[j] = f2bf(Ts[(bq * 8 + j) * 65 + rl]);
            *(short8*)(xT + (size_t)(kt * 64 + rl) * 256 + bg * 64 + bq * 8) = o.v;
        }
        // xB[b][k]
#pragma unroll
        for (int r = 0; r < 2; ++r) {
            const int flat = r * 256 + tid;
            const int b = flat >> 3, g = flat & 7;
            union { short8 v; unsigned short h[8]; } o;
#pragma unroll
            for (int j = 0; j < 8; ++j) o.h[j] = f2bf(Ts[b * 65 + g * 8 + j]);
            *(short8*)(xB + (size_t)(bg * 64 + b) * KP + (size_t)kt * 64 + g * 8) = o.v;
        }
    } else {
        __shared__ float Ws[8 * 1032];
        const int i0 = (blockIdx.x - 1204) * 8;
#pragma unroll
        for (int r = 0; r < 8; ++r) {
            const int flat = r * 256 + tid;
            const int g = flat >> 8, rem = flat & 255;
            int gi = i0 + g; if (gi > 2400) gi = 2400;
            const float4 v = *(const float4*)(W + (size_t)gi * 1024 + rem * 4);
            *(float4*)&Ws[g * 1032 + rem * 4] = v;
        }
        __syncthreads();
#pragma unroll
        for (int r = 0; r < 4; ++r) {
            const int flat = r * 256 + tid;
            const int oc = flat >> 3, g = flat & 7;
            const int gi = i0 + g;
            union { short8 v; unsigned short h[8]; } w, c;
            if (gi <= 2400) {
                const float* wp = &Ws[g * 1032 + oc * 8];
#pragma unroll
                for (int j = 0; j < 8; ++j) {
                    w.h[j] = f2bf(wp[j]);
                    c.h[j] = f2bf(0.125f * wp[j]);
                }
            } else {
#pragma unroll
                for (int j = 0; j < 8; ++j) { w.h[j] = 0; c.h[j] = 0; }
            }
            *(short8*)(Wbf + (size_t)oc * KP + (size_t)gi * 8) = w.v;
            *(short8*)(cwt + (size_t)oc * KP + (size_t)gi * 8) = c.v;
        }
    }
}

// ---------------- s: s[b][oc] += sum_k xB[b,k]*cwt[oc,k], split-K via fp32 atomics.
// grid (8 bg, NI) = 512 blocks (2/CU). Block 32b x 128oc; wave 16b x 64oc (2x2 waves).
__global__ __launch_bounds__(256, 2)
void s_gemm(const unsigned short* __restrict__ xB, const unsigned short* __restrict__ cwt,
            float* __restrict__ s)
{
    __shared__ __align__(16) unsigned short Xs[32 * 64];    // 4 KB
    __shared__ __align__(16) unsigned short Bs[128 * 64];   // 16 KB
    const int tid = threadIdx.x;
    const int b0  = blockIdx.x * 32;
    const int iy  = blockIdx.y;
    const int ln  = tid & 63;
    const int mr  = ln & 15, qd = ln >> 4;
    const int wv  = tid >> 6;
    const int mh  = wv & 1;          // 16-b half
    const int nh  = wv >> 1;         // 64-oc half

    f32x4 acc[4];
#pragma unroll
    for (int n = 0; n < 4; ++n) acc[n] = (f32x4){0.f, 0.f, 0.f, 0.f};

    for (int kt = iy; kt < KTILES; kt += NI) {
        __syncthreads();
        {   // Xs: 256 granules, 1/thread
            const int b = tid >> 3, g = tid & 7;
            const short8 v = *(const short8*)(xB + (size_t)(b0 + b) * KP + (size_t)(kt * 8 + g) * 8);
            *(short8*)&Xs[b * 64 + ((g ^ (b & 7)) * 8)] = v;
        }
#pragma unroll
        for (int r = 0; r < 4; ++r) {   // Bs: 1024 granules, 4/thread
            const int flat = r * 256 + tid;
            const int oc = flat >> 3, g = flat & 7;
            const short8 w = *(const short8*)(cwt + (size_t)oc * KP + (size_t)(kt * 8 + g) * 8);
            *(short8*)&Bs[oc * 64 + ((g ^ (oc & 7)) * 8)] = w;
        }
        __syncthreads();
#pragma unroll
        for (int kk = 0; kk < 2; ++kk) {
            const int csw = ((kk * 4 + qd) ^ (mr & 7)) * 8;
            const short8 a = *(const short8*)&Xs[(mh * 16 + mr) * 64 + csw];
#pragma unroll
            for (int nt = 0; nt < 4; ++nt) {
                const short8 b = *(const short8*)&Bs[(nh * 64 + nt * 16 + mr) * 64 + csw];
                acc[nt] = __builtin_amdgcn_mfma_f32_16x16x32_bf16(a, b, acc[nt], 0, 0, 0);
            }
        }
    }

#pragma unroll
    for (int nt = 0; nt < 4; ++nt)
#pragma unroll
        for (int r = 0; r < 4; ++r)
            unsafeAtomicAdd(&s[(size_t)(b0 + mh * 16 + qd * 4 + r) * OCC + nh * 64 + nt * 16 + mr],
                            acc[nt][r]);
}

// ---------------- agreement: in-block squash(s)->As bf16 [oc][b] (full 256 b in LDS),
// H[oc][(i,d)] = sum_b As*xT (MFMA), then a[i,o] = (1/256) sum W*H, softmax, write cwt.
template<bool FIRST>
__global__ __launch_bounds__(256, 2)
void a_gemm(const unsigned short* __restrict__ xT, const float* __restrict__ s,
            const unsigned short* __restrict__ Wbf, float* __restrict__ bij,
            unsigned short* __restrict__ cwt)
{
    __shared__ __align__(16) unsigned short As[128 * 256];  // 64 KB; Hs aliases it later
    __shared__ __align__(16) unsigned short Bx[64 * 64];    // 8 KB
    float* Hs = (float*)As;                                 // [128][68] = 34816 B

    const int tid = threadIdx.x;
    const int i0  = blockIdx.x * 8;
    const int ln  = tid & 63, wv = tid >> 6;
    const int mr  = ln & 15, qd = ln >> 4;

    // ---- phase A: squash. thread (q=t&3, g=t>>2): b-quad 4g..4g+3, o in {2q,2q+1}.
    {
        const int q = tid & 3, g = tid >> 2;
        const int gh = g >> 1, gl = g & 1;
#pragma unroll
        for (int oh = 0; oh < 2; ++oh) {
            const int o = q * 2 + oh;
            float va[4][16];
            float sc[4];
#pragma unroll
            for (int rb = 0; rb < 4; ++rb) {
                const float4* sr = (const float4*)(s + (size_t)(g * 4 + rb) * OCC + o * 16);
                const float4 t0 = sr[0], t1 = sr[1], t2 = sr[2], t3 = sr[3];
                va[rb][0] = t0.x; va[rb][1] = t0.y; va[rb][2]  = t0.z; va[rb][3]  = t0.w;
                va[rb][4] = t1.x; va[rb][5] = t1.y; va[rb][6]  = t1.z; va[rb][7]  = t1.w;
                va[rb][8] = t2.x; va[rb][9] = t2.y; va[rb][10] = t2.z; va[rb][11] = t2.w;
                va[rb][12] = t3.x; va[rb][13] = t3.y; va[rb][14] = t3.z; va[rb][15] = t3.w;
                float ms = 0.0f;
#pragma unroll
                for (int j = 0; j < 16; ++j) ms = fmaf(va[rb][j], va[rb][j], ms);
                sc[rb] = sqrtf(ms) / (1.0f + ms);   // == mag_sq/(1+mag_sq)/mag
            }
#pragma unroll
            for (int c = 0; c < 16; ++c) {
                const int oc = o * 16 + c;
                short4v pk;
                pk[0] = (short)f2bf(va[0][c] * sc[0]);
                pk[1] = (short)f2bf(va[1][c] * sc[1]);
                pk[2] = (short)f2bf(va[2][c] * sc[2]);
                pk[3] = (short)f2bf(va[3][c] * sc[3]);
                *(short4v*)&As[oc * 256 + ((gh ^ (oc & 7)) * 8) + gl * 4] = pk;
            }
        }
    }

    // ---- phase B: H GEMM over 4 batch-chunks of 64
    f32x4 acc[2][4];
#pragma unroll
    for (int a = 0; a < 2; ++a)
#pragma unroll
        for (int b = 0; b < 4; ++b) acc[a][b] = (f32x4){0.f, 0.f, 0.f, 0.f};

    for (int bc = 0; bc < 4; ++bc) {
        __syncthreads();                       // also covers phase-A completion (bc=0)
#pragma unroll
        for (int r = 0; r < 2; ++r) {          // Bx <- xT rows i0*8..+63, cols bc*64..
            const int flat = r * 256 + tid;
            const int rw = flat >> 3, col = flat & 7;
            const short8 v = *(const short8*)(xT + (size_t)(i0 * 8 + rw) * 256 + bc * 64 + col * 8);
            *(short8*)&Bx[rw * 64 + ((col ^ (rw & 7)) * 8)] = v;
        }
        __syncthreads();
#pragma unroll
        for (int kk = 0; kk < 2; ++kk) {
            const int gr  = bc * 8 + kk * 4 + qd;       // As column-granule
            const int csw = ((kk * 4 + qd) ^ (mr & 7)) * 8;
            short8 a[2];
#pragma unroll
            for (int mt = 0; mt < 2; ++mt) {
                const int arow = (wv * 2 + mt) * 16 + mr;
                a[mt] = *(const short8*)&As[arow * 256 + ((gr ^ (arow & 7)) * 8)];
            }
#pragma unroll
            for (int nt = 0; nt < 4; ++nt) {
                const short8 b = *(const short8*)&Bx[(nt * 16 + mr) * 64 + csw];
#pragma unroll
                for (int mt = 0; mt < 2; ++mt)
                    acc[mt][nt] = __builtin_amdgcn_mfma_f32_16x16x32_bf16(a[mt], b, acc[mt][nt], 0, 0, 0);
            }
        }
    }

    __syncthreads();                           // As fully consumed; Hs may alias
#pragma unroll
    for (int mt = 0; mt < 2; ++mt)
#pragma unroll
        for (int nt = 0; nt < 4; ++nt)
#pragma unroll
            for (int r = 0; r < 4; ++r)
                Hs[((wv * 2 + mt) * 16 + qd * 4 + r) * 68 + nt * 16 + mr] = acc[mt][nt][r];
    __syncthreads();

    // ---- phase C: tid = il*32 + oo*4 + ch
    const int ch = tid & 3, oo = (tid >> 2) & 7, il = tid >> 5;
    const int ival = i0 + il;
    const int gi = (ival < IC) ? ival : IC - 1;
    const unsigned short* Wt = Wbf + (size_t)(oo * 16 + ch * 4) * KP + (size_t)gi * 8;

    float wreg[4][8];
#pragma unroll
    for (int c = 0; c < 4; ++c) {
        union { short8 v; unsigned short h[8]; } uw;
        uw.v = *(const short8*)(Wt + (size_t)c * KP);
#pragma unroll
        for (int j = 0; j < 8; ++j) wreg[c][j] = bf2f(uw.h[j]);
    }
    float p = 0.0f;
#pragma unroll
    for (int c = 0; c < 4; ++c) {
        const float* hr = &Hs[(oo * 16 + ch * 4 + c) * 68 + il * 8];
        const float4 h0 = *(const float4*)hr;
        const float4 h1 = *(const float4*)(hr + 4);
        p = fmaf(wreg[c][0], h0.x, p); p = fmaf(wreg[c][1], h0.y, p);
        p = fmaf(wreg[c][2], h0.z, p); p = fmaf(wreg[c][3], h0.w, p);
        p = fmaf(wreg[c][4], h1.x, p); p = fmaf(wreg[c][5], h1.y, p);
        p = fmaf(wreg[c][6], h1.z, p); p = fmaf(wreg[c][7], h1.w, p);
    }
    p += __shfl_xor(p, 1); p += __shfl_xor(p, 2);   // combine ch quarters
    const float anew = p * (1.0f / 256.0f);
    float bv = anew;
    if (!FIRST) bv += bij[gi * 8 + oo];
    float mx = bv;                                   // softmax over oo (bits 2..4)
    mx = fmaxf(mx, __shfl_xor(mx, 4));
    mx = fmaxf(mx, __shfl_xor(mx, 8));
    mx = fmaxf(mx, __shfl_xor(mx, 16));
    const float e = expf(bv - mx);
    float ss = e;
    ss += __shfl_xor(ss, 4); ss += __shfl_xor(ss, 8); ss += __shfl_xor(ss, 16);
    float cv = e / ss;
    if (ival >= IC) cv = 0.0f;                       // keep cwt pad rows zero
    if (ch == 0 && ival < IC) bij[ival * 8 + oo] = bv;
#pragma unroll
    for (int c = 0; c < 4; ++c) {
        union { short8 v; unsigned short h[8]; } o;
#pragma unroll
        for (int j = 0; j < 8; ++j) o.h[j] = f2bf(cv * wreg[c][j]);
        *(short8*)(cwt + (size_t)(oo * 16 + ch * 4 + c) * KP + (size_t)ival * 8) = o.v;
    }
}

// ---------------- final: squash(s2) -> out fp32 [b][o][c]
__global__ __launch_bounds__(256)
void final_kernel(const float* __restrict__ s, float* __restrict__ out)
{
    const int row = blockIdx.x * 256 + threadIdx.x;   // 0..2047 = b*8+o
    const float4* p = (const float4*)(s + (size_t)row * CS);
    const float4 t0 = p[0], t1 = p[1], t2 = p[2], t3 = p[3];
    float ms = 0.0f;
    ms = fmaf(t0.x, t0.x, ms); ms = fmaf(t0.y, t0.y, ms);
    ms = fmaf(t0.z, t0.z, ms); ms = fmaf(t0.w, t0.w, ms);
    ms = fmaf(t1.x, t1.x, ms); ms = fmaf(t1.y, t1.y, ms);
    ms = fmaf(t1.z, t1.z, ms); ms = fmaf(t1.w, t1.w, ms);
    ms = fmaf(t2.x, t2.x, ms); ms = fmaf(t2.y, t2.y, ms);
    ms = fmaf(t2.z, t2.z, ms); ms = fmaf(t2.w, t2.w, ms);
    ms = fmaf(t3.x, t3.x, ms); ms = fmaf(t3.y, t3.y, ms);
    ms = fmaf(t3.z, t3.z, ms); ms = fmaf(t3.w, t3.w, ms);
    const float sc = sqrtf(ms) / (1.0f + ms);
    float4* o4 = (float4*)(out + (size_t)row * CS);
    o4[0] = make_float4(t0.x * sc, t0.y * sc, t0.z * sc, t0.w * sc);
    o4[1] = make_float4(t1.x * sc, t1.y * sc, t1.z * sc, t1.w * sc);
    o4[2] = make_float4(t2.x * sc, t2.y * sc, t2.z * sc, t2.w * sc);
    o4[3] = make_float4(t3.x * sc, t3.y * sc, t3.z * sc, t3.w * sc);
}

extern "C" void kernel_launch(void* const* d_in, const int* in_sizes, int n_in,
                              void* d_out, int out_size, void* d_ws, size_t ws_size,
                              hipStream_t stream)
{
    const float* x = (const float*)d_in[0];   // [256, 2401, 8]
    const float* W = (const float*)d_in[1];   // [2401, 8, 16, 8]
    float* out = (float*)d_out;               // [256, 8, 16]

    char* p = (char*)d_ws;
    float*          sbuf = (float*)p;           p += 3 * (size_t)BSZ * OCC * 4;    // 384 KB
    unsigned short* xT   = (unsigned short*)p;  p += (size_t)KP * 256 * 2;         // 9.86 MB
    unsigned short* xB   = (unsigned short*)p;  p += (size_t)256 * KP * 2;         // 9.86 MB
    unsigned short* Wbf  = (unsigned short*)p;  p += (size_t)128 * KP * 2;         // 4.93 MB
    unsigned short* cwt  = (unsigned short*)p;  p += (size_t)128 * KP * 2;         // 4.93 MB
    float*          bij  = (float*)p;                                             // 77 KB

    float* s0 = sbuf;
    float* s1 = sbuf + (size_t)BSZ * OCC;
    float* s2 = sbuf + 2 * (size_t)BSZ * OCC;

    const dim3 sgrid(8, NI);

    prep_kernel<<<1505, 256, 0, stream>>>(x, W, xT, xB, Wbf, cwt, sbuf);

    s_gemm<<<sgrid, 256, 0, stream>>>(xB, cwt, s0);
    a_gemm<true><<<KTILES, 256, 0, stream>>>(xT, s0, Wbf, bij, cwt);

    s_gemm<<<sgrid, 256, 0, stream>>>(xB, cwt, s1);
    a_gemm<false><<<KTILES, 256, 0, stream>>>(xT, s1, Wbf, bij, cwt);

    s_gemm<<<sgrid, 256, 0, stream>>>(xB, cwt, s2);
    final_kernel<<<8, 256, 0, stream>>>(s2, out);
}